// Round 9
// baseline (203.957 us; speedup 1.0000x reference)
//
#include <hip/hip_runtime.h>
#include <math.h>

#define N_ 2048
#define D_ 1024
#define TOPK 10
#define TOPK_HALF 5
#define NTRI 528
#define INV_NORM (1.0f / ((float)N_ * (float)(N_ - 1)))

typedef __attribute__((ext_vector_type(8))) short short8;
typedef __attribute__((ext_vector_type(16))) float floatx16;

__device__ __forceinline__ short f2bf(float f) {
  unsigned u = __float_as_uint(f);
  unsigned r = (u + 0x7fffu + ((u >> 16) & 1u)) >> 16;
  return (short)r;
}
__device__ __forceinline__ float bf2f(short b) {
  return __uint_as_float(((unsigned)(unsigned short)b) << 16);
}

// ---------- prep: normalize t -> bf16 (+tt), convert s -> bf16 (+ss); zero rowsum & out ----------
__global__ __launch_bounds__(256) void prep_kernel(const float* __restrict__ t,
                                                   const float* __restrict__ s,
                                                   short* __restrict__ tb,
                                                   short* __restrict__ sb,
                                                   float* __restrict__ tt,
                                                   float* __restrict__ ss,
                                                   float* __restrict__ rowsum,
                                                   float* __restrict__ out) {
  int b = blockIdx.x, tid = threadIdx.x;
  __shared__ float red[256];
  if (b == 0) {
    for (int j = tid; j < N_; j += 256) rowsum[j] = 0.f;
    if (tid == 0) out[0] = 0.f;
  }
  if (b < N_) {  // tnorm row b
    const float4* rp = (const float4*)(t + (size_t)b * D_);
    float4 v = rp[tid];
    red[tid] = v.x * v.x + v.y * v.y + v.z * v.z + v.w * v.w;
    __syncthreads();
    for (int st = 128; st > 0; st >>= 1) { if (tid < st) red[tid] += red[tid + st]; __syncthreads(); }
    float inv = 1.f / fmaxf(sqrtf(red[0]), 1e-12f);
    __syncthreads();
    float a = v.x * inv, bb = v.y * inv, c = v.z * inv, d = v.w * inv;
    uint2 pk;
    pk.x = (unsigned)(unsigned short)f2bf(a) | ((unsigned)(unsigned short)f2bf(bb) << 16);
    pk.y = (unsigned)(unsigned short)f2bf(c) | ((unsigned)(unsigned short)f2bf(d) << 16);
    ((uint2*)(tb + (size_t)b * D_))[tid] = pk;
    red[tid] = a * a + bb * bb + c * c + d * d;
    __syncthreads();
    for (int st = 128; st > 0; st >>= 1) { if (tid < st) red[tid] += red[tid + st]; __syncthreads(); }
    if (tid == 0) tt[b] = red[0];
  } else {  // sconv row b-N_
    int row = b - N_;
    const float4* rp = (const float4*)(s + (size_t)row * D_);
    float4 v = rp[tid];
    uint2 pk;
    pk.x = (unsigned)(unsigned short)f2bf(v.x) | ((unsigned)(unsigned short)f2bf(v.y) << 16);
    pk.y = (unsigned)(unsigned short)f2bf(v.z) | ((unsigned)(unsigned short)f2bf(v.w) << 16);
    ((uint2*)(sb + (size_t)row * D_))[tid] = pk;
    red[tid] = v.x * v.x + v.y * v.y + v.z * v.z + v.w * v.w;
    __syncthreads();
    for (int st = 128; st > 0; st >>= 1) { if (tid < st) red[tid] += red[tid + st]; __syncthreads(); }
    if (tid == 0) ss[row] = red[0];
  }
}

// ---------- symmetric bf16-MFMA Gram: global->VGPR fragments, no LDS K-loop, no barriers ----------
// Inputs (4 MB each) are L2-resident; each lane loads its 16B A/B frag directly.
__global__ __launch_bounds__(256) void gram_sym_kernel(
    const short* __restrict__ Tb, const short* __restrict__ Sb,
    const float* __restrict__ tt, const float* __restrict__ ss,
    short* __restrict__ WPb, short* __restrict__ Sob,
    float* __restrict__ rowsum) {
  int p = blockIdx.x;
  const int mode = (p >= NTRI);
  int q = p - mode * NTRI;
  int bi = (int)((sqrtf(8.f * (float)q + 1.f) - 1.f) * 0.5f);
  if (bi > 31) bi = 31;
  while ((bi + 1) * (bi + 2) / 2 <= q) bi++;
  while (bi * (bi + 1) / 2 > q) bi--;
  int bj = q - bi * (bi + 1) / 2;  // 0 <= bj <= bi

  const short* A = mode ? Sb : Tb;
  const float* rn = mode ? ss : tt;
  short* outb = mode ? Sob : WPb;

  __shared__ __align__(16) float smem[4 * 1088];  // wave-private transpose scratch

  int tid = threadIdx.x;
  int w = tid >> 6, lane = tid & 63;
  int i0 = bi * 64, j0 = bj * 64;
  int wr = w >> 1, wc = w & 1;
  int l32 = lane & 31, half = lane >> 5;

  floatx16 acc = {};

  // A-frag for 32x32x16: lane -> row (wr*32+l32), K-chunk [k0 + half*8, +8)
  const short* Arow = A + (size_t)(i0 + wr * 32 + l32) * D_ + half * 8;
  const short* Brow = A + (size_t)(j0 + wc * 32 + l32) * D_ + half * 8;

#pragma unroll 8
  for (int k0 = 0; k0 < D_; k0 += 16) {
    short8 af = *(const short8*)(Arow + k0);
    short8 bfr = *(const short8*)(Brow + k0);
    acc = __builtin_amdgcn_mfma_f32_32x32x16_bf16(af, bfr, acc, 0, 0, 0);
  }

  // ---- epilogue: activate, direct store, row sums; then transposed tile ----
  // C/D: col = l32, row_local = (reg&3) + 8*(reg>>2) + 4*half
  float ov[16];
  int jcol = j0 + wc * 32 + l32;
  float rj = rn[jcol];
#pragma unroll
  for (int reg = 0; reg < 16; reg++) {
    int rl = (reg & 3) + 8 * (reg >> 2) + 4 * half;
    int i = i0 + wr * 32 + rl;
    float d2 = fmaxf(rn[i] + rj - 2.f * acc[reg], 0.f);
    float o = mode ? sqrtf(d2) : expf(-d2);
    if (i == jcol) o = mode ? 0.f : 1.f;
    ov[reg] = o;
    outb[(size_t)i * N_ + jcol] = f2bf(o);
  }
  if (mode) {
#pragma unroll
    for (int reg = 0; reg < 16; reg++) {
      float rs = ov[reg];
      rs += __shfl_xor(rs, 1); rs += __shfl_xor(rs, 2);
      rs += __shfl_xor(rs, 4); rs += __shfl_xor(rs, 8);
      rs += __shfl_xor(rs, 16);
      if (l32 == 0) {
        int rl = (reg & 3) + 8 * (reg >> 2) + 4 * half;
        atomicAdd(&rowsum[i0 + wr * 32 + rl], rs);
      }
    }
  }

  if (bi != bj) {
    if (mode) {
      float cs = 0.f;
#pragma unroll
      for (int reg = 0; reg < 16; reg++) cs += ov[reg];
      cs += __shfl_xor(cs, 32);
      if (half == 0) atomicAdd(&rowsum[jcol], cs);
    }
    // transposed store via wave-private LDS scratch (no barriers needed)
    float* fs = smem + w * 1088;  // 32x32 fp32, pad 34
#pragma unroll
    for (int reg = 0; reg < 16; reg++) {
      int rl = (reg & 3) + 8 * (reg >> 2) + 4 * half;
      fs[l32 * 34 + rl] = ov[reg];
    }
#pragma unroll
    for (int itx = 0; itx < 8; itx++) {
      int sidx = itx * 64 + lane;
      int lc = sidx >> 4;        // transposed row (= original col)
      int k2 = (sidx & 15) * 2;  // original-row pair
      float lo = fs[lc * 34 + k2];
      float hi = fs[lc * 34 + k2 + 1];
      unsigned pk = (unsigned)(unsigned short)f2bf(lo) |
                    ((unsigned)(unsigned short)f2bf(hi) << 16);
      size_t jg = (size_t)(j0 + wc * 32 + lc);
      *(unsigned*)(outb + jg * N_ + i0 + wr * 32 + k2) = pk;
    }
  }
}

// ---------- wave-per-row: dense loss partial + register-resident top-10 ----------
__global__ __launch_bounds__(64) void topk_loss_kernel(const short* __restrict__ WPb,
                                                       const short* __restrict__ Sb,
                                                       const float* __restrict__ rowsum,
                                                       int* __restrict__ idx,
                                                       float* __restrict__ out) {
  int row = blockIdx.x, lane = threadIdx.x;
  const short8* wpr = (const short8*)(WPb + (size_t)row * N_);
  const short8* sr = (const short8*)(Sb + (size_t)row * N_);
  float rminv = (float)N_ / rowsum[row];
  float w[32];
  float local = 0.f;
#pragma unroll
  for (int c4 = 0; c4 < 4; c4++) {
    short8 wp8 = wpr[lane * 4 + c4];
    short8 s8 = sr[lane * 4 + c4];
#pragma unroll
    for (int e = 0; e < 8; e++) {
      float wv = bf2f(wp8[e]);
      w[c4 * 8 + e] = wv;
      float sv = bf2f(s8[e]) * rminv;
      float d = fmaxf(1.f - sv, 0.f);
      local += d * d + 0.5f * wv * (sv * sv - d * d);
    }
  }
#pragma unroll
  for (int off = 32; off > 0; off >>= 1) local += __shfl_down(local, off);
  if (lane == 0) atomicAdd(out, (local - 0.5f) * INV_NORM);  // subtract diag term
  int base = lane * 32;
  int sel[TOPK];
  for (int t = 0; t < TOPK; t++) {
    float bv = -2.f; int bi = 0;
#pragma unroll
    for (int c = 0; c < 32; c++)
      if (w[c] > bv) { bv = w[c]; bi = base + c; }
#pragma unroll
    for (int off = 32; off > 0; off >>= 1) {
      float ovv = __shfl_down(bv, off);
      int oi = __shfl_down(bi, off);
      if (ovv > bv || (ovv == bv && oi < bi)) { bv = ovv; bi = oi; }
    }
    bi = __shfl(bi, 0);
    sel[t] = bi;
    bool mine = (bi >> 5) == lane;
    int cc = bi & 31;
#pragma unroll
    for (int c = 0; c < 32; c++)
      if (mine && cc == c) w[c] = -1.f;
  }
  if (lane == 0) {
#pragma unroll
    for (int t = 0; t < TOPK; t++) idx[row * TOPK + t] = sel[t];
  }
}

// ---------- mutual mask for row x, recomputed inline ----------
__device__ __forceinline__ unsigned mutual_mask(const int* __restrict__ idx, int x) {
  unsigned m = 0;
  int nb[TOPK];
#pragma unroll
  for (int k = 0; k < TOPK; k++) nb[k] = idx[x * TOPK + k];
#pragma unroll
  for (int k = 0; k < TOPK; k++) {
    int j = nb[k];
    bool mut = false;
#pragma unroll
    for (int l = 0; l < TOPK; l++) mut |= (idx[j * TOPK + l] == x);
    if (mut) m |= 1u << k;
  }
  return m;
}

// ---------- sparse W_C part: one thread per (i, mi, k); mutual computed inline ----------
__global__ __launch_bounds__(256) void sparse_wc_kernel(
    const int* __restrict__ idx, const short* __restrict__ Sb,
    const float* __restrict__ rowsum, float* __restrict__ out) {
  int t = blockIdx.x * 256 + threadIdx.x;
  int i = t >> 6, r = t & 63;
  float contrib = 0.f;
  if (i < N_ && r < TOPK_HALF * TOPK) {
    int mi = r / TOPK, k = r - mi * TOPK;
    int m = idx[i * TOPK + mi];
    unsigned mm = mutual_mask(idx, m);
    if ((mm >> k) & 1u) {
      int col = idx[m * TOPK + k];
      if (col != i) {
        int dm = __popc(mm);
        unsigned mc = mutual_mask(idx, col);
        int jm[TOPK], jc[TOPK];
#pragma unroll
        for (int l = 0; l < TOPK; l++) jm[l] = idx[m * TOPK + l];
#pragma unroll
        for (int l = 0; l < TOPK; l++) jc[l] = idx[col * TOPK + l];
        int c = 0;
#pragma unroll
        for (int a = 0; a < TOPK; a++) {
          if ((mm >> a) & 1u) {
            int na = jm[a];
#pragma unroll
            for (int b = 0; b < TOPK; b++) c += (((mc >> b) & 1u) && (jc[b] == na));
          }
        }
        float v = (float)c / (float)dm * 0.1f;  // (1/5 mean) * (1/2 symmetrize)
        float s1 = bf2f(Sb[(size_t)i * N_ + col]) * ((float)N_ / rowsum[i]);
        float d1 = fmaxf(1.f - s1, 0.f);
        float s2 = bf2f(Sb[(size_t)col * N_ + i]) * ((float)N_ / rowsum[col]);
        float d2 = fmaxf(1.f - s2, 0.f);
        contrib = 0.5f * v * ((s1 * s1 - d1 * d1) + (s2 * s2 - d2 * d2));
      }
    }
  }
  __shared__ float red[256];
  red[threadIdx.x] = contrib; __syncthreads();
  for (int st = 128; st > 0; st >>= 1) {
    if (threadIdx.x < st) red[threadIdx.x] += red[threadIdx.x + st];
    __syncthreads();
  }
  if (threadIdx.x == 0) atomicAdd(out, red[0] * INV_NORM);
}

extern "C" void kernel_launch(void* const* d_in, const int* in_sizes, int n_in,
                              void* d_out, int out_size, void* d_ws, size_t ws_size,
                              hipStream_t stream) {
  const float* s_emb = (const float*)d_in[0];
  const float* t_emb = (const float*)d_in[1];
  float* out = (float*)d_out;

  const size_t NN = (size_t)N_ * N_;
  const size_t ND = (size_t)N_ * D_;
  short* t_bf = (short*)d_ws;                        // N*D bf16
  short* s_bf = t_bf + ND;                           // N*D bf16
  short* WPb = s_bf + ND;                            // N*N bf16
  short* Sb = WPb + NN;                              // N*N bf16
  float* tt = (float*)(Sb + NN);                     // N
  float* ss = tt + N_;                               // N
  float* rowsum = ss + N_;                           // N
  int* idx = (int*)(rowsum + N_);                    // N*TOPK

  prep_kernel<<<2 * N_, 256, 0, stream>>>(t_emb, s_emb, t_bf, s_bf, tt, ss, rowsum, out);

  gram_sym_kernel<<<2 * NTRI, 256, 0, stream>>>(t_bf, s_bf, tt, ss, WPb, Sb, rowsum);

  topk_loss_kernel<<<N_, 64, 0, stream>>>(WPb, Sb, rowsum, idx, out);
  sparse_wc_kernel<<<N_ * 64 / 256, 256, 0, stream>>>(idx, Sb, rowsum, out);
}

// Round 10
// 158.561 us; speedup vs baseline: 1.2863x; 1.2863x over previous
//
#include <hip/hip_runtime.h>
#include <math.h>

#define N_ 2048
#define D_ 1024
#define TOPK 10
#define TOPK_HALF 5
#define NTRI 528
#define INV_NORM (1.0f / ((float)N_ * (float)(N_ - 1)))

typedef __attribute__((ext_vector_type(8))) short short8;
typedef __attribute__((ext_vector_type(16))) float floatx16;

__device__ __forceinline__ short f2bf(float f) {
  unsigned u = __float_as_uint(f);
  unsigned r = (u + 0x7fffu + ((u >> 16) & 1u)) >> 16;
  return (short)r;
}
__device__ __forceinline__ float bf2f(short b) {
  return __uint_as_float(((unsigned)(unsigned short)b) << 16);
}

__device__ __forceinline__ void gld_lds16(const short* g, short* l) {
  __builtin_amdgcn_global_load_lds(
      (const __attribute__((address_space(1))) unsigned int*)(g),
      (__attribute__((address_space(3))) unsigned int*)(l), 16, 0, 0);
}

#define BAR() asm volatile("s_barrier" ::: "memory")
#define WAIT12_BAR() asm volatile("s_waitcnt vmcnt(12)\ns_barrier" ::: "memory")
#define WAIT8_BAR() asm volatile("s_waitcnt vmcnt(8)\ns_barrier" ::: "memory")
#define WAIT4_BAR() asm volatile("s_waitcnt vmcnt(4)\ns_barrier" ::: "memory")
#define WAIT0_BAR() asm volatile("s_waitcnt vmcnt(0)\ns_barrier" ::: "memory")

// ---------- prep: normalize t -> bf16 (+tt), convert s -> bf16 (+ss); zero rowsum & out ----------
__global__ __launch_bounds__(256) void prep_kernel(const float* __restrict__ t,
                                                   const float* __restrict__ s,
                                                   short* __restrict__ tb,
                                                   short* __restrict__ sb,
                                                   float* __restrict__ tt,
                                                   float* __restrict__ ss,
                                                   float* __restrict__ rowsum,
                                                   float* __restrict__ out) {
  int b = blockIdx.x, tid = threadIdx.x;
  __shared__ float red[256];
  if (b == 0) {
    for (int j = tid; j < N_; j += 256) rowsum[j] = 0.f;
    if (tid == 0) out[0] = 0.f;
  }
  if (b < N_) {  // tnorm row b
    const float4* rp = (const float4*)(t + (size_t)b * D_);
    float4 v = rp[tid];
    red[tid] = v.x * v.x + v.y * v.y + v.z * v.z + v.w * v.w;
    __syncthreads();
    for (int st = 128; st > 0; st >>= 1) { if (tid < st) red[tid] += red[tid + st]; __syncthreads(); }
    float inv = 1.f / fmaxf(sqrtf(red[0]), 1e-12f);
    __syncthreads();
    float a = v.x * inv, bb = v.y * inv, c = v.z * inv, d = v.w * inv;
    uint2 pk;
    pk.x = (unsigned)(unsigned short)f2bf(a) | ((unsigned)(unsigned short)f2bf(bb) << 16);
    pk.y = (unsigned)(unsigned short)f2bf(c) | ((unsigned)(unsigned short)f2bf(d) << 16);
    ((uint2*)(tb + (size_t)b * D_))[tid] = pk;
    red[tid] = a * a + bb * bb + c * c + d * d;
    __syncthreads();
    for (int st = 128; st > 0; st >>= 1) { if (tid < st) red[tid] += red[tid + st]; __syncthreads(); }
    if (tid == 0) tt[b] = red[0];
  } else {  // sconv row b-N_
    int row = b - N_;
    const float4* rp = (const float4*)(s + (size_t)row * D_);
    float4 v = rp[tid];
    uint2 pk;
    pk.x = (unsigned)(unsigned short)f2bf(v.x) | ((unsigned)(unsigned short)f2bf(v.y) << 16);
    pk.y = (unsigned)(unsigned short)f2bf(v.z) | ((unsigned)(unsigned short)f2bf(v.w) << 16);
    ((uint2*)(sb + (size_t)row * D_))[tid] = pk;
    red[tid] = v.x * v.x + v.y * v.y + v.z * v.z + v.w * v.w;
    __syncthreads();
    for (int st = 128; st > 0; st >>= 1) { if (tid < st) red[tid] += red[tid + st]; __syncthreads(); }
    if (tid == 0) ss[row] = red[0];
  }
}

// ---------- symmetric bf16-MFMA Gram: 64x64 triangle tiles, 4-buffer LDS ring, depth-3 prefetch ----------
__global__ __launch_bounds__(256) void gram_sym_kernel(
    const short* __restrict__ Tb, const short* __restrict__ Sb,
    const float* __restrict__ tt, const float* __restrict__ ss,
    short* __restrict__ WPb, short* __restrict__ Sob,
    float* __restrict__ rowsum) {
  int p = blockIdx.x;
  const int mode = (p >= NTRI);
  int q = p - mode * NTRI;
  int bi = (int)((sqrtf(8.f * (float)q + 1.f) - 1.f) * 0.5f);
  if (bi > 31) bi = 31;
  while ((bi + 1) * (bi + 2) / 2 <= q) bi++;
  while (bi * (bi + 1) / 2 > q) bi--;
  int bj = q - bi * (bi + 1) / 2;  // 0 <= bj <= bi

  const short* A = mode ? Sb : Tb;
  const float* rn = mode ? ss : tt;
  short* outb = mode ? Sob : WPb;

  // 4 ring buffers x (A 64x64 + B 64x64) bf16 = 64 KB
  __shared__ __align__(16) short smem[4 * 8192];

  int tid = threadIdx.x;
  int w = tid >> 6, lane = tid & 63;
  int i0 = bi * 64, j0 = bj * 64;
  int wr = w >> 1, wc = w & 1;
  int l32 = lane & 31, half = lane >> 5;

  floatx16 acc = {};

  // staging: wave w stages rows [w*16, w*16+16), XOR chunk swizzle; 4 loads/stage
  int sr8 = lane >> 3;
  int gch = ((lane & 7) ^ sr8) * 8;
  const short* Ag = A + (size_t)(i0 + w * 16 + sr8) * D_ + gch;
  const short* Bg = A + (size_t)(j0 + w * 16 + sr8) * D_ + gch;
  int lloc = (w * 16 + sr8) * 64 + (lane & 7) * 8;

#define STAGE(buf, k0)                                       \
  do {                                                       \
    short* Al = smem + (buf)*8192 + lloc;                    \
    short* Bl = smem + (buf)*8192 + 4096 + lloc;             \
    gld_lds16(Ag + (k0), Al);                                \
    gld_lds16(Ag + (k0) + (size_t)8 * D_, Al + 512);         \
    gld_lds16(Bg + (k0), Bl);                                \
    gld_lds16(Bg + (k0) + (size_t)8 * D_, Bl + 512);         \
  } while (0)

  STAGE(0, 0);
  STAGE(1, 64);
  STAGE(2, 128);
#pragma unroll
  for (int it = 0; it < 16; it++) {
    if (it) BAR();  // all waves done computing stage it-1 -> its ring slot is free
    if (it + 3 < 16) STAGE((it + 3) & 3, (it + 3) * 64);
    // wait only for stage `it` (FIFO): leave later stages' loads in flight
    if (it < 13) WAIT12_BAR();
    else if (it == 13) WAIT8_BAR();
    else if (it == 14) WAIT4_BAR();
    else WAIT0_BAR();
    const short* Ab = smem + (it & 3) * 8192;
    const short* Bb = smem + (it & 3) * 8192 + 4096;
#pragma unroll
    for (int kstep = 0; kstep < 4; kstep++) {
      int cA = (((2 * kstep + half) ^ (l32 & 7)) << 3);
      short8 af = *(const short8*)&Ab[(wr * 32 + l32) * 64 + cA];
      short8 bfr = *(const short8*)&Bb[(wc * 32 + l32) * 64 + cA];
      acc = __builtin_amdgcn_mfma_f32_32x32x16_bf16(af, bfr, acc, 0, 0, 0);
    }
  }

  // ---- epilogue: activate, direct store, row sums; then transposed tile ----
  // C/D: col = l32, row_local = (reg&3) + 8*(reg>>2) + 4*half
  float ov[16];
  int jcol = j0 + wc * 32 + l32;
  float rj = rn[jcol];
#pragma unroll
  for (int reg = 0; reg < 16; reg++) {
    int rl = (reg & 3) + 8 * (reg >> 2) + 4 * half;
    int i = i0 + wr * 32 + rl;
    float d2 = fmaxf(rn[i] + rj - 2.f * acc[reg], 0.f);
    float o = mode ? sqrtf(d2) : expf(-d2);
    if (i == jcol) o = mode ? 0.f : 1.f;
    ov[reg] = o;
    outb[(size_t)i * N_ + jcol] = f2bf(o);
  }
  if (mode) {
#pragma unroll
    for (int reg = 0; reg < 16; reg++) {
      float rs = ov[reg];
      rs += __shfl_xor(rs, 1); rs += __shfl_xor(rs, 2);
      rs += __shfl_xor(rs, 4); rs += __shfl_xor(rs, 8);
      rs += __shfl_xor(rs, 16);
      if (l32 == 0) {
        int rl = (reg & 3) + 8 * (reg >> 2) + 4 * half;
        atomicAdd(&rowsum[i0 + wr * 32 + rl], rs);
      }
    }
  }

  if (bi != bj) {
    if (mode) {
      float cs = 0.f;
#pragma unroll
      for (int reg = 0; reg < 16; reg++) cs += ov[reg];
      cs += __shfl_xor(cs, 32);
      if (half == 0) atomicAdd(&rowsum[jcol], cs);
    }
    BAR();  // K-loop slab reads done before scratch overwrite
    float* fs = (float*)smem + w * 1088;  // 32x32 fp32, pad 34, per wave
#pragma unroll
    for (int reg = 0; reg < 16; reg++) {
      int rl = (reg & 3) + 8 * (reg >> 2) + 4 * half;
      fs[l32 * 34 + rl] = ov[reg];
    }
#pragma unroll
    for (int itx = 0; itx < 8; itx++) {
      int sidx = itx * 64 + lane;
      int lc = sidx >> 4;        // transposed row (= original col)
      int k2 = (sidx & 15) * 2;  // original-row pair
      float lo = fs[lc * 34 + k2];
      float hi = fs[lc * 34 + k2 + 1];
      unsigned pk = (unsigned)(unsigned short)f2bf(lo) |
                    ((unsigned)(unsigned short)f2bf(hi) << 16);
      size_t jg = (size_t)(j0 + wc * 32 + lc);
      *(unsigned*)(outb + jg * N_ + i0 + wr * 32 + k2) = pk;
    }
  }
}

// ---------- wave-per-row: dense loss partial + register-resident top-10 ----------
__global__ __launch_bounds__(64) void topk_loss_kernel(const short* __restrict__ WPb,
                                                       const short* __restrict__ Sb,
                                                       const float* __restrict__ rowsum,
                                                       int* __restrict__ idx,
                                                       unsigned* __restrict__ mask,
                                                       float* __restrict__ out) {
  int row = blockIdx.x, lane = threadIdx.x;
  const short8* wpr = (const short8*)(WPb + (size_t)row * N_);
  const short8* sr = (const short8*)(Sb + (size_t)row * N_);
  float rminv = (float)N_ / rowsum[row];
  float w[32];
  float local = 0.f;
#pragma unroll
  for (int c4 = 0; c4 < 4; c4++) {
    short8 wp8 = wpr[lane * 4 + c4];
    short8 s8 = sr[lane * 4 + c4];
#pragma unroll
    for (int e = 0; e < 8; e++) {
      float wv = bf2f(wp8[e]);
      w[c4 * 8 + e] = wv;
      float sv = bf2f(s8[e]) * rminv;
      float d = fmaxf(1.f - sv, 0.f);
      local += d * d + 0.5f * wv * (sv * sv - d * d);
    }
  }
#pragma unroll
  for (int off = 32; off > 0; off >>= 1) local += __shfl_down(local, off);
  if (lane == 0) {
    atomicAdd(out, (local - 0.5f) * INV_NORM);  // subtract diag term
    mask[row] = 0u;
  }
  int base = lane * 32;
  int sel[TOPK];
  for (int t = 0; t < TOPK; t++) {
    float bv = -2.f; int bi = 0;
#pragma unroll
    for (int c = 0; c < 32; c++)
      if (w[c] > bv) { bv = w[c]; bi = base + c; }
#pragma unroll
    for (int off = 32; off > 0; off >>= 1) {
      float ovv = __shfl_down(bv, off);
      int oi = __shfl_down(bi, off);
      if (ovv > bv || (ovv == bv && oi < bi)) { bv = ovv; bi = oi; }
    }
    bi = __shfl(bi, 0);
    sel[t] = bi;
    bool mine = (bi >> 5) == lane;
    int cc = bi & 31;
#pragma unroll
    for (int c = 0; c < 32; c++)
      if (mine && cc == c) w[c] = -1.f;
  }
  if (lane == 0) {
#pragma unroll
    for (int t = 0; t < TOPK; t++) idx[row * TOPK + t] = sel[t];
  }
}

// ---------- mutual kNN as bitmask: one thread per (i,k) ----------
__global__ __launch_bounds__(256) void mutual_kernel(const int* __restrict__ idx,
                                                     unsigned* __restrict__ mask) {
  int t = blockIdx.x * 256 + threadIdx.x;
  int i = t >> 4, k = t & 15;
  if (i >= N_ || k >= TOPK) return;
  int j = idx[i * TOPK + k];
  bool mut = false;
#pragma unroll
  for (int l = 0; l < TOPK; l++) mut |= (idx[j * TOPK + l] == i);
  if (mut) atomicOr(&mask[i], 1u << k);
}

// ---------- sparse W_C part via masks: one thread per (i, mi, k) ----------
__global__ __launch_bounds__(256) void sparse_wc_kernel(
    const int* __restrict__ idx, const unsigned* __restrict__ mask,
    const short* __restrict__ Sb, const float* __restrict__ rowsum,
    float* __restrict__ out) {
  int t = blockIdx.x * 256 + threadIdx.x;
  int i = t >> 6, r = t & 63;
  float contrib = 0.f;
  if (i < N_ && r < TOPK_HALF * TOPK) {
    int mi = r / TOPK, k = r - mi * TOPK;
    int m = idx[i * TOPK + mi];
    unsigned mm = mask[m];
    if ((mm >> k) & 1u) {
      int col = idx[m * TOPK + k];
      if (col != i) {
        int dm = __popc(mm);
        unsigned mc = mask[col];
        int jm[TOPK], jc[TOPK];
#pragma unroll
        for (int l = 0; l < TOPK; l++) jm[l] = idx[m * TOPK + l];
#pragma unroll
        for (int l = 0; l < TOPK; l++) jc[l] = idx[col * TOPK + l];
        int c = 0;
#pragma unroll
        for (int a = 0; a < TOPK; a++) {
          if ((mm >> a) & 1u) {
            int na = jm[a];
#pragma unroll
            for (int b = 0; b < TOPK; b++) c += (((mc >> b) & 1u) && (jc[b] == na));
          }
        }
        float v = (float)c / (float)dm * 0.1f;  // (1/5 mean) * (1/2 symmetrize)
        float s1 = bf2f(Sb[(size_t)i * N_ + col]) * ((float)N_ / rowsum[i]);
        float d1 = fmaxf(1.f - s1, 0.f);
        float s2 = bf2f(Sb[(size_t)col * N_ + i]) * ((float)N_ / rowsum[col]);
        float d2 = fmaxf(1.f - s2, 0.f);
        contrib = 0.5f * v * ((s1 * s1 - d1 * d1) + (s2 * s2 - d2 * d2));
      }
    }
  }
  __shared__ float red[256];
  red[threadIdx.x] = contrib; __syncthreads();
  for (int st = 128; st > 0; st >>= 1) {
    if (threadIdx.x < st) red[threadIdx.x] += red[threadIdx.x + st];
    __syncthreads();
  }
  if (threadIdx.x == 0) atomicAdd(out, red[0] * INV_NORM);
}

extern "C" void kernel_launch(void* const* d_in, const int* in_sizes, int n_in,
                              void* d_out, int out_size, void* d_ws, size_t ws_size,
                              hipStream_t stream) {
  const float* s_emb = (const float*)d_in[0];
  const float* t_emb = (const float*)d_in[1];
  float* out = (float*)d_out;

  const size_t NN = (size_t)N_ * N_;
  const size_t ND = (size_t)N_ * D_;
  short* t_bf = (short*)d_ws;                        // N*D bf16
  short* s_bf = t_bf + ND;                           // N*D bf16
  short* WPb = s_bf + ND;                            // N*N bf16
  short* Sb = WPb + NN;                              // N*N bf16
  float* tt = (float*)(Sb + NN);                     // N
  float* ss = tt + N_;                               // N
  float* rowsum = ss + N_;                           // N
  int* idx = (int*)(rowsum + N_);                    // N*TOPK
  unsigned* mask = (unsigned*)(idx + (size_t)N_ * TOPK);  // N

  prep_kernel<<<2 * N_, 256, 0, stream>>>(t_emb, s_emb, t_bf, s_bf, tt, ss, rowsum, out);

  gram_sym_kernel<<<2 * NTRI, 256, 0, stream>>>(t_bf, s_bf, tt, ss, WPb, Sb, rowsum);

  topk_loss_kernel<<<N_, 64, 0, stream>>>(WPb, Sb, rowsum, idx, mask, out);
  mutual_kernel<<<N_ * 16 / 256, 256, 0, stream>>>(idx, mask);
  sparse_wc_kernel<<<N_ * 64 / 256, 256, 0, stream>>>(idx, mask, Sb, rowsum, out);
}

// Round 12
// 150.232 us; speedup vs baseline: 1.3576x; 1.0554x over previous
//
#include <hip/hip_runtime.h>
#include <math.h>

#define N_ 2048
#define D_ 1024
#define TOPK 10
#define TOPK_HALF 5
#define NTRI2 136
#define INV_NORM (1.0f / ((float)N_ * (float)(N_ - 1)))

typedef __attribute__((ext_vector_type(8))) short short8;
typedef __attribute__((ext_vector_type(16))) float floatx16;

__device__ __forceinline__ short f2bf(float f) {
  unsigned u = __float_as_uint(f);
  unsigned r = (u + 0x7fffu + ((u >> 16) & 1u)) >> 16;
  return (short)r;
}
__device__ __forceinline__ float bf2f(short b) {
  return __uint_as_float(((unsigned)(unsigned short)b) << 16);
}

__device__ __forceinline__ void gld_lds16(const short* g, short* l) {
  __builtin_amdgcn_global_load_lds(
      (const __attribute__((address_space(1))) unsigned int*)(g),
      (__attribute__((address_space(3))) unsigned int*)(l), 16, 0, 0);
}

#define BAR() asm volatile("s_barrier" ::: "memory")
#define WAIT4_BAR() asm volatile("s_waitcnt vmcnt(4)\ns_barrier" ::: "memory")
#define WAIT0_BAR() asm volatile("s_waitcnt vmcnt(0)\ns_barrier" ::: "memory")

// ---------- prep: normalize t -> bf16 (+tt), convert s -> bf16 (+ss); zero rowsum & out ----------
__global__ __launch_bounds__(256) void prep_kernel(const float* __restrict__ t,
                                                   const float* __restrict__ s,
                                                   short* __restrict__ tb,
                                                   short* __restrict__ sb,
                                                   float* __restrict__ tt,
                                                   float* __restrict__ ss,
                                                   float* __restrict__ rowsum,
                                                   float* __restrict__ out) {
  int b = blockIdx.x, tid = threadIdx.x;
  __shared__ float red[256];
  if (b == 0) {
    for (int j = tid; j < N_; j += 256) rowsum[j] = 0.f;
    if (tid == 0) out[0] = 0.f;
  }
  if (b < N_) {  // tnorm row b
    const float4* rp = (const float4*)(t + (size_t)b * D_);
    float4 v = rp[tid];
    red[tid] = v.x * v.x + v.y * v.y + v.z * v.z + v.w * v.w;
    __syncthreads();
    for (int st = 128; st > 0; st >>= 1) { if (tid < st) red[tid] += red[tid + st]; __syncthreads(); }
    float inv = 1.f / fmaxf(sqrtf(red[0]), 1e-12f);
    __syncthreads();
    float a = v.x * inv, bb = v.y * inv, c = v.z * inv, d = v.w * inv;
    uint2 pk;
    pk.x = (unsigned)(unsigned short)f2bf(a) | ((unsigned)(unsigned short)f2bf(bb) << 16);
    pk.y = (unsigned)(unsigned short)f2bf(c) | ((unsigned)(unsigned short)f2bf(d) << 16);
    ((uint2*)(tb + (size_t)b * D_))[tid] = pk;
    red[tid] = a * a + bb * bb + c * c + d * d;
    __syncthreads();
    for (int st = 128; st > 0; st >>= 1) { if (tid < st) red[tid] += red[tid + st]; __syncthreads(); }
    if (tid == 0) tt[b] = red[0];
  } else {  // sconv row b-N_
    int row = b - N_;
    const float4* rp = (const float4*)(s + (size_t)row * D_);
    float4 v = rp[tid];
    uint2 pk;
    pk.x = (unsigned)(unsigned short)f2bf(v.x) | ((unsigned)(unsigned short)f2bf(v.y) << 16);
    pk.y = (unsigned)(unsigned short)f2bf(v.z) | ((unsigned)(unsigned short)f2bf(v.w) << 16);
    ((uint2*)(sb + (size_t)row * D_))[tid] = pk;
    red[tid] = v.x * v.x + v.y * v.y + v.z * v.z + v.w * v.w;
    __syncthreads();
    for (int st = 128; st > 0; st >>= 1) { if (tid < st) red[tid] += red[tid + st]; __syncthreads(); }
    if (tid == 0) ss[row] = red[0];
  }
}

// ---------- symmetric bf16-MFMA Gram: 128x128 triangle tiles, 512 threads, dbuf BK=64 ----------
// Halves L3 panel traffic vs 64-tiles (270 -> ~139 MB): the measured ~5.7 TB/s L3 ceiling
// was the R4-R10 invariant. Wave w: rows rt*32 (rt=w&3), cols ch*64 (ch=w>>2), 2x 32x32 MFMA.
__global__ __launch_bounds__(512) void gram_sym_kernel(
    const short* __restrict__ Tb, const short* __restrict__ Sb,
    const float* __restrict__ tt, const float* __restrict__ ss,
    short* __restrict__ WPb, short* __restrict__ Sob,
    float* __restrict__ rowsum) {
  int p = blockIdx.x;
  const int mode = (p >= NTRI2);
  int q = p - mode * NTRI2;
  int bi = (int)((sqrtf(8.f * (float)q + 1.f) - 1.f) * 0.5f);
  if (bi > 15) bi = 15;
  while ((bi + 1) * (bi + 2) / 2 <= q) bi++;
  while (bi * (bi + 1) / 2 > q) bi--;
  int bj = q - bi * (bi + 1) / 2;  // 0 <= bj <= bi

  const short* A = mode ? Sb : Tb;
  const float* rn = mode ? ss : tt;
  short* outb = mode ? Sob : WPb;

  // dbuf: [buf][A 128x64 | B 128x64] bf16 = 2 x 32 KB = 64 KB
  __shared__ __align__(16) short smem[2 * 16384];

  int tid = threadIdx.x;
  int w = tid >> 6, lane = tid & 63;
  int i0 = bi * 128, j0 = bj * 128;
  int rt = w & 3, ch = w >> 2;
  int l32 = lane & 31, half = lane >> 5;

  floatx16 acc[2] = {};

  // staging: wave w stages A rows [w*16, w*16+16) and same B rows; XOR chunk swizzle
  int sr8 = lane >> 3;
  int gch = ((lane & 7) ^ sr8) * 8;
  const short* Ag = A + (size_t)(i0 + w * 16 + sr8) * D_ + gch;
  const short* Bg = A + (size_t)(j0 + w * 16 + sr8) * D_ + gch;
  int lloc = (w * 16 + sr8) * 64 + (lane & 7) * 8;

#define STAGE(buf, k0)                                       \
  do {                                                       \
    short* Al = smem + (buf)*16384 + lloc;                   \
    short* Bl = smem + (buf)*16384 + 8192 + lloc;            \
    gld_lds16(Ag + (k0), Al);                                \
    gld_lds16(Ag + (k0) + (size_t)8 * D_, Al + 512);         \
    gld_lds16(Bg + (k0), Bl);                                \
    gld_lds16(Bg + (k0) + (size_t)8 * D_, Bl + 512);         \
  } while (0)

  STAGE(0, 0);
#pragma unroll
  for (int it = 0; it < 16; it++) {
    int cur = it & 1;
    if (it) BAR();  // all waves done with buf[cur] from 2 iters ago -> safe to overwrite
    if (it < 15) {
      STAGE(!cur, (it + 1) * 64);
      WAIT4_BAR();  // wait stage `it`'s 4 loads; leave next stage's 4 in flight
    } else {
      WAIT0_BAR();
    }
    const short* Ab = smem + cur * 16384;
    const short* Bb = smem + cur * 16384 + 8192;
#pragma unroll
    for (int kstep = 0; kstep < 4; kstep++) {
      int cb = 2 * kstep + half;
      int phys = ((cb ^ (l32 & 7)) << 3);
      short8 af = *(const short8*)&Ab[(rt * 32 + l32) * 64 + phys];
      short8 b0 = *(const short8*)&Bb[(ch * 64 + l32) * 64 + phys];
      short8 b1 = *(const short8*)&Bb[(ch * 64 + 32 + l32) * 64 + phys];
      acc[0] = __builtin_amdgcn_mfma_f32_32x32x16_bf16(af, b0, acc[0], 0, 0, 0);
      acc[1] = __builtin_amdgcn_mfma_f32_32x32x16_bf16(af, b1, acc[1], 0, 0, 0);
    }
  }

  // ---- epilogue: activate, direct store, row sums; then transposed tiles ----
  // C/D: col = l32 (B-row), row_local = (reg&3) + 8*(reg>>2) + 4*half (A-row)
  float ov[2][16];
  int ibase = i0 + rt * 32;
#pragma unroll
  for (int nt = 0; nt < 2; nt++) {
    int jcol = j0 + ch * 64 + nt * 32 + l32;
    float rj = rn[jcol];
#pragma unroll
    for (int reg = 0; reg < 16; reg++) {
      int rl = (reg & 3) + 8 * (reg >> 2) + 4 * half;
      int i = ibase + rl;
      float d2 = fmaxf(rn[i] + rj - 2.f * acc[nt][reg], 0.f);
      float o = mode ? sqrtf(d2) : expf(-d2);
      if (i == jcol) o = mode ? 0.f : 1.f;
      ov[nt][reg] = o;
      outb[(size_t)i * N_ + jcol] = f2bf(o);
    }
  }
  if (mode) {
#pragma unroll
    for (int reg = 0; reg < 16; reg++) {
      float rs = ov[0][reg] + ov[1][reg];
      rs += __shfl_xor(rs, 1); rs += __shfl_xor(rs, 2);
      rs += __shfl_xor(rs, 4); rs += __shfl_xor(rs, 8);
      rs += __shfl_xor(rs, 16);
      if (l32 == 0) {
        int rl = (reg & 3) + 8 * (reg >> 2) + 4 * half;
        atomicAdd(&rowsum[ibase + rl], rs);
      }
    }
  }

  if (bi != bj) {
    if (mode) {
#pragma unroll
      for (int nt = 0; nt < 2; nt++) {
        float cs = 0.f;
#pragma unroll
        for (int reg = 0; reg < 16; reg++) cs += ov[nt][reg];
        cs += __shfl_xor(cs, 32);
        if (half == 0) atomicAdd(&rowsum[j0 + ch * 64 + nt * 32 + l32], cs);
      }
    }
    BAR();  // all waves past K-loop reads before scratch overwrites slabs
    float* fs = (float*)smem + w * 1088;  // 32x34 fp32 per wave
#pragma unroll
    for (int nt = 0; nt < 2; nt++) {
#pragma unroll
      for (int reg = 0; reg < 16; reg++) {
        int rl = (reg & 3) + 8 * (reg >> 2) + 4 * half;
        fs[l32 * 34 + rl] = ov[nt][reg];
      }
#pragma unroll
      for (int itx = 0; itx < 8; itx++) {
        int sidx = itx * 64 + lane;
        int lc = sidx >> 4;        // transposed row (= original col)
        int k2 = (sidx & 15) * 2;  // original-row pair
        float lo = fs[lc * 34 + k2];
        float hi = fs[lc * 34 + k2 + 1];
        unsigned pk = (unsigned)(unsigned short)f2bf(lo) |
                      ((unsigned)(unsigned short)f2bf(hi) << 16);
        size_t jg = (size_t)(j0 + ch * 64 + nt * 32 + lc);
        *(unsigned*)(outb + jg * N_ + ibase + k2) = pk;
      }
    }
  }
}

// ---------- wave-per-row: dense loss partial + register-resident top-10 ----------
__global__ __launch_bounds__(64) void topk_loss_kernel(const short* __restrict__ WPb,
                                                       const short* __restrict__ Sb,
                                                       const float* __restrict__ rowsum,
                                                       int* __restrict__ idx,
                                                       unsigned* __restrict__ mask,
                                                       float* __restrict__ out) {
  int row = blockIdx.x, lane = threadIdx.x;
  const short8* wpr = (const short8*)(WPb + (size_t)row * N_);
  const short8* sr = (const short8*)(Sb + (size_t)row * N_);
  float rminv = (float)N_ / rowsum[row];
  float w[32];
  float local = 0.f;
#pragma unroll
  for (int c4 = 0; c4 < 4; c4++) {
    short8 wp8 = wpr[lane * 4 + c4];
    short8 s8 = sr[lane * 4 + c4];
#pragma unroll
    for (int e = 0; e < 8; e++) {
      float wv = bf2f(wp8[e]);
      w[c4 * 8 + e] = wv;
      float sv = bf2f(s8[e]) * rminv;
      float d = fmaxf(1.f - sv, 0.f);
      local += d * d + 0.5f * wv * (sv * sv - d * d);
    }
  }
#pragma unroll
  for (int off = 32; off > 0; off >>= 1) local += __shfl_down(local, off);
  if (lane == 0) {
    atomicAdd(out, (local - 0.5f) * INV_NORM);  // subtract diag term
    mask[row] = 0u;
  }
  int base = lane * 32;
  int sel[TOPK];
  for (int t = 0; t < TOPK; t++) {
    float bv = -2.f; int bi = 0;
#pragma unroll
    for (int c = 0; c < 32; c++)
      if (w[c] > bv) { bv = w[c]; bi = base + c; }
#pragma unroll
    for (int off = 32; off > 0; off >>= 1) {
      float ovv = __shfl_down(bv, off);
      int oi = __shfl_down(bi, off);
      if (ovv > bv || (ovv == bv && oi < bi)) { bv = ovv; bi = oi; }
    }
    bi = __shfl(bi, 0);
    sel[t] = bi;
    bool mine = (bi >> 5) == lane;
    int cc = bi & 31;
#pragma unroll
    for (int c = 0; c < 32; c++)
      if (mine && cc == c) w[c] = -1.f;
  }
  if (lane == 0) {
#pragma unroll
    for (int t = 0; t < TOPK; t++) idx[row * TOPK + t] = sel[t];
  }
}

// ---------- mutual kNN as bitmask: one thread per (i,k) ----------
__global__ __launch_bounds__(256) void mutual_kernel(const int* __restrict__ idx,
                                                     unsigned* __restrict__ mask) {
  int t = blockIdx.x * 256 + threadIdx.x;
  int i = t >> 4, k = t & 15;
  if (i >= N_ || k >= TOPK) return;
  int j = idx[i * TOPK + k];
  bool mut = false;
#pragma unroll
  for (int l = 0; l < TOPK; l++) mut |= (idx[j * TOPK + l] == i);
  if (mut) atomicOr(&mask[i], 1u << k);
}

// ---------- sparse W_C part via masks: one thread per (i, mi, k) ----------
__global__ __launch_bounds__(256) void sparse_wc_kernel(
    const int* __restrict__ idx, const unsigned* __restrict__ mask,
    const short* __restrict__ Sb, const float* __restrict__ rowsum,
    float* __restrict__ out) {
  int t = blockIdx.x * 256 + threadIdx.x;
  int i = t >> 6, r = t & 63;
  float contrib = 0.f;
  if (i < N_ && r < TOPK_HALF * TOPK) {
    int mi = r / TOPK, k = r - mi * TOPK;
    int m = idx[i * TOPK + mi];
    unsigned mm = mask[m];
    if ((mm >> k) & 1u) {
      int col = idx[m * TOPK + k];
      if (col != i) {
        int dm = __popc(mm);
        unsigned mc = mask[col];
        int jm[TOPK], jc[TOPK];
#pragma unroll
        for (int l = 0; l < TOPK; l++) jm[l] = idx[m * TOPK + l];
#pragma unroll
        for (int l = 0; l < TOPK; l++) jc[l] = idx[col * TOPK + l];
        int c = 0;
#pragma unroll
        for (int a = 0; a < TOPK; a++) {
          if ((mm >> a) & 1u) {
            int na = jm[a];
#pragma unroll
            for (int b = 0; b < TOPK; b++) c += (((mc >> b) & 1u) && (jc[b] == na));
          }
        }
        float v = (float)c / (float)dm * 0.1f;  // (1/5 mean) * (1/2 symmetrize)
        float s1 = bf2f(Sb[(size_t)i * N_ + col]) * ((float)N_ / rowsum[i]);
        float d1 = fmaxf(1.f - s1, 0.f);
        float s2 = bf2f(Sb[(size_t)col * N_ + i]) * ((float)N_ / rowsum[col]);
        float d2 = fmaxf(1.f - s2, 0.f);
        contrib = 0.5f * v * ((s1 * s1 - d1 * d1) + (s2 * s2 - d2 * d2));
      }
    }
  }
  __shared__ float red[256];
  red[threadIdx.x] = contrib; __syncthreads();
  for (int st = 128; st > 0; st >>= 1) {
    if (threadIdx.x < st) red[threadIdx.x] += red[threadIdx.x + st];
    __syncthreads();
  }
  if (threadIdx.x == 0) atomicAdd(out, red[0] * INV_NORM);
}

extern "C" void kernel_launch(void* const* d_in, const int* in_sizes, int n_in,
                              void* d_out, int out_size, void* d_ws, size_t ws_size,
                              hipStream_t stream) {
  const float* s_emb = (const float*)d_in[0];
  const float* t_emb = (const float*)d_in[1];
  float* out = (float*)d_out;

  const size_t NN = (size_t)N_ * N_;
  const size_t ND = (size_t)N_ * D_;
  short* t_bf = (short*)d_ws;                        // N*D bf16
  short* s_bf = t_bf + ND;                           // N*D bf16
  short* WPb = s_bf + ND;                            // N*N bf16
  short* Sb = WPb + NN;                              // N*N bf16
  float* tt = (float*)(Sb + NN);                     // N
  float* ss = tt + N_;                               // N
  float* rowsum = ss + N_;                           // N
  int* idx = (int*)(rowsum + N_);                    // N*TOPK
  unsigned* mask = (unsigned*)(idx + (size_t)N_ * TOPK);  // N

  prep_kernel<<<2 * N_, 256, 0, stream>>>(t_emb, s_emb, t_bf, s_bf, tt, ss, rowsum, out);

  gram_sym_kernel<<<2 * NTRI2, 512, 0, stream>>>(t_bf, s_bf, tt, ss, WPb, Sb, rowsum);

  topk_loss_kernel<<<N_, 64, 0, stream>>>(WPb, Sb, rowsum, idx, mask, out);
  mutual_kernel<<<N_ * 16 / 256, 256, 0, stream>>>(idx, mask);
  sparse_wc_kernel<<<N_ * 64 / 256, 256, 0, stream>>>(idx, mask, Sb, rowsum, out);
}